// Round 8
// baseline (3786.002 us; speedup 1.0000x reference)
//
#include <hip/hip_runtime.h>

// LSTM: N=64, T=1024, D=512, H=512. out (N,T,H) fp32 = h_{t+1} for t=0..T-1.
//
// R8: 64 wgs x 512 thr (8 waves). Each wg: 16 batch rows x 32 h-cols.
//   Row-group = 16 wgs (was 32): convoy max halves. h transport: R6/R7
//   self-announcing tagged u32 words (fp16 bits<<16 | gen tag), 2-slot ring.
//   Poll: 256 sync threads x 16 u64 (was 128 x 32) with SELECTIVE re-poll
//   (retry rounds reload only unready words). Wave roles:
//     waves 0-3 (sync): x/h MFMA, poll+stage h, epilogue, h-store, houts.
//       vm queue: poll loads + own h-store acks only.
//     waves 4-7 (x): x/h MFMA, x prefetch (8 float4), ALL out HBM stores
//       (rows 0-7 via houts one step late, rows 8-15 own, direct),
//       vmcnt(0) only before x-cvt where x-loads are ~1400cy aged.
//   2 barriers/step. Transport bits identical -> absmax 0.00390625 canary.

#define TT 1024
#define NB 64
#define DD 512
#define HH 512
#define XROW 520           // 512 + 8 pad (elems)
#define NBHH (NB * HH)
#define TTDD (TT * DD)

typedef _Float16 half8 __attribute__((ext_vector_type(8)));
typedef _Float16 half4 __attribute__((ext_vector_type(4)));
typedef float floatx4 __attribute__((ext_vector_type(4)));
typedef unsigned long long u64;
typedef unsigned int u32;
typedef unsigned short u16;

#define AQ __ATOMIC_RELAXED
#define SC __HIP_MEMORY_SCOPE_AGENT

// Fill both ring slots with tag 0xFFFF (matches no generation).
__global__ void init_ws_kernel(u64* hq) {
    hq[blockIdx.x * 256 + threadIdx.x] = 0x0000FFFF0000FFFFULL;  // 32768 u64
}

__device__ __forceinline__ void barrier_lgkm() {
    asm volatile("s_waitcnt lgkmcnt(0)" ::: "memory");
    __builtin_amdgcn_s_barrier();
    asm volatile("" ::: "memory");
}

#define MFMA16(A, B, C) __builtin_amdgcn_mfma_f32_16x16x32_f16((A), (B), (C), 0, 0, 0)

__global__ __launch_bounds__(512, 1) void lstm_persist(
    const float* __restrict__ x, const float* __restrict__ h0,
    const float* __restrict__ Wx, const float* __restrict__ Wh,
    const float* __restrict__ b, float* __restrict__ out,
    u64* __restrict__ hq)
{
    const int tid  = threadIdx.x;
    const int lane = tid & 63;
    const int wave = tid >> 6;          // 0..7
    const int gate = wave & 3;          // i,f,o,g
    const int ch   = wave >> 2;         // col-half within the wg's 32 cols
    const int cg   = blockIdx.x & 15;   // col group: h-cols cg*32..+31
    const int rg   = blockIdx.x >> 4;   // row group: batch rows rg*16..+15
    const int row0 = rg << 4;

    __shared__ __align__(16) _Float16 xbuf[2][16 * XROW];  // x_t / x_{t+1}
    __shared__ __align__(16) _Float16 hlds[16 * XROW];     // h_t rows (fp16)
    __shared__ float gatebuf[4 * 16 * 33];                 // 4 gates x 16 x 33
    __shared__ float houts[2][256];                        // rows 0-7 hv handoff

    // ---- persistent B fragments: this wave's 16 a-cols, K=1024 ----
    const int bcol = (gate << 9) + (cg << 5) + (ch << 4) + (lane & 15);
    const int kq   = (lane >> 4) << 3;
    half8 bfrag[32];
#pragma unroll
    for (int kt = 0; kt < 16; ++kt)
#pragma unroll
        for (int j = 0; j < 8; ++j)
            bfrag[kt][j] = (_Float16)Wx[(size_t)((kt << 5) + kq + j) * 2048 + bcol];
#pragma unroll
    for (int kt = 16; kt < 32; ++kt)
#pragma unroll
        for (int j = 0; j < 8; ++j)
            bfrag[kt][j] = (_Float16)Wh[(size_t)((kt << 5) + kq + j - 512) * 2048 + bcol];

    // ---- per-thread output element: (er, ec) of the 16x32 tile ----
    const int er = tid >> 5;            // 0..15
    const int ec = tid & 31;            // 0..31
    const int gn = row0 + er;           // global batch row
    const int gh = (cg << 5) + ec;      // global h col
    const float bi = b[0 * 512 + gh];
    const float bf = b[1 * 512 + gh];
    const float bo = b[2 * 512 + gh];
    const float bg = b[3 * 512 + gh];
    float c_state = 0.f;

    const bool isx = tid >= 256;        // waves 4-7: x/out pipeline
    const int pr = (tid >> 4) & 15;     // sync poll row 0..15
    const int pc = tid & 15;            // sync poll col-slot 0..15
    const int xtid = tid & 255;         // x-role index 0..255
    const int xr = xtid >> 4;           // x row 0..15
    const int xc = xtid & 15;           // x float4 slot 0..15

    const int arow = (lane & 15) * XROW + kq;

    // ---- prologue: x-waves stage x_0; all publish h_0 (gen 0) ----
    if (isx) {
        const float4* xs = (const float4*)(x + (size_t)(row0 + xr) * TTDD);
        _Float16* xd = xbuf[0] + xr * XROW;
#pragma unroll
        for (int j = 0; j < 8; ++j) {
            float4 v = xs[xc + (j << 4)];
            half4 hc;
            hc.x = (_Float16)v.x; hc.y = (_Float16)v.y;
            hc.z = (_Float16)v.z; hc.w = (_Float16)v.w;
            *(half4*)&xd[(xc + (j << 4)) << 2] = hc;
        }
    }
    {
        float hv0 = h0[(size_t)gn * HH + gh];
        float pn  = __shfl_down(hv0, 1);
        if ((ec & 1) == 0) {
            _Float16 f0 = (_Float16)hv0, f1 = (_Float16)pn;
            u16 b0, b1;
            __builtin_memcpy(&b0, &f0, 2); __builtin_memcpy(&b1, &f1, 2);
            const u32 wtag = 0xB000u;   // gen 0: slot 0, tag bit 0
            u32 lo = ((u32)b0 << 16) | wtag;
            u32 hi = ((u32)b1 << 16) | wtag;
            u64 v = (u64)lo | ((u64)hi << 32);
            __hip_atomic_store(hq + (size_t)gn * 256 + (gh >> 1), v, AQ, SC);
        }
    }
    barrier_lgkm();   // xbuf[0] + h_0 visible

    for (int t = 0; t < TT; ++t) {
        const bool havex = (t + 1 < TT);

        // ---- 1. x-waves: issue x_{t+1} loads (aged ~1400cy by cvt time) ----
        float4 xvv[8];
        if (isx && havex) {
            const float4* xsrc = (const float4*)(x + (size_t)(row0 + xr) * TTDD
                                                 + (size_t)(t + 1) * DD);
#pragma unroll
            for (int j = 0; j < 8; ++j)
                xvv[j] = xsrc[xc + (j << 4)];
        }

        // ---- 2. x-part MFMA from xbuf[t&1] (all waves, LDS only) ----
        floatx4 acc0 = {0.f, 0.f, 0.f, 0.f};
        floatx4 acc1 = {0.f, 0.f, 0.f, 0.f};
        const _Float16* xa = xbuf[t & 1];
#pragma unroll
        for (int kt = 0; kt < 16; kt += 2) {
            half8 a0 = *(const half8*)&xa[arow + (kt << 5)];
            half8 a1 = *(const half8*)&xa[arow + ((kt + 1) << 5)];
            acc0 = MFMA16(a0, bfrag[kt],     acc0);
            acc1 = MFMA16(a1, bfrag[kt + 1], acc1);
        }

        // ---- 3. sync waves: selective poll of 16 tagged u64; stage ----
        if (!isx) {
            const u64 wantp = ((u64)(0xB000u | ((u32)(t >> 1) & 1u)))
                              * 0x0000000100000001ULL;
            const u64* src = hq + (size_t)(t & 1) * (NBHH / 2)
                           + (size_t)(row0 + pr) * 256 + pc;
            u64 w[16];
            unsigned rdy = 0;
            do {
#pragma unroll
                for (int j = 0; j < 16; ++j)
                    if (!((rdy >> j) & 1u))
                        w[j] = __hip_atomic_load(src + (j << 4), AQ, SC);
#pragma unroll
                for (int j = 0; j < 16; ++j)
                    if (!((rdy >> j) & 1u)
                        && ((w[j] ^ wantp) & 0x0000FFFF0000FFFFULL) == 0)
                        rdy |= 1u << j;
            } while (rdy != 0xFFFFu);
            u32* dst = (u32*)hlds + pr * 260 + pc;
#pragma unroll
            for (int j = 0; j < 16; ++j) {
                u32 lo = (u32)w[j] >> 16;
                u32 hi = (u32)(w[j] >> 32) & 0xFFFF0000u;
                dst[j << 4] = lo | hi;      // col pair (2W, 2W+1), W = pc+16j
            }
        }
        barrier_lgkm();   // A: h tile staged

        // ---- 4. x-waves: pick up handed hv (rows 0-7, step t-1) ----
        float hprev = 0.f;
        if (isx && t > 0) hprev = houts[(t - 1) & 1][xtid];

        // ---- 5. h-part MFMA (all waves) ----
#pragma unroll
        for (int kt = 0; kt < 16; kt += 2) {
            half8 a0 = *(const half8*)&hlds[arow + (kt << 5)];
            half8 a1 = *(const half8*)&hlds[arow + ((kt + 1) << 5)];
            acc0 = MFMA16(a0, bfrag[16 + kt],     acc0);
            acc1 = MFMA16(a1, bfrag[16 + kt + 1], acc1);
        }
        floatx4 acc = acc0 + acc1;

        // ---- 6. gate exchange: C/D col=lane&15, row=quad*4+v ----
        {
            const int ccol = (ch << 4) + (lane & 15);
            const int crow = (lane >> 4) << 2;
#pragma unroll
            for (int v = 0; v < 4; ++v)
                gatebuf[gate * 528 + (crow + v) * 33 + ccol] = acc[v];
        }

        // ---- 7. x-waves: cvt x_{t+1} -> LDS; then out stores (fire-forget) ----
        if (isx) {
            if (havex) {
                asm volatile("s_waitcnt vmcnt(0)" ::: "memory");  // x loads aged
                _Float16* xd = xbuf[(t + 1) & 1] + xr * XROW;
                half4 hc;
#pragma unroll
                for (int j = 0; j < 8; ++j) {
                    float4 v = xvv[j];
                    hc.x = (_Float16)v.x; hc.y = (_Float16)v.y;
                    hc.z = (_Float16)v.z; hc.w = (_Float16)v.w;
                    *(half4*)&xd[(xc + (j << 4)) << 2] = hc;
                }
            }
            if (t > 0) {   // handed rows 0-7 of step t-1
                out[(size_t)(row0 + (xtid >> 5)) * (TT * HH)
                    + (size_t)(t - 1) * HH + (cg << 5) + (xtid & 31)] = hprev;
            }
        }
        barrier_lgkm();   // B: gatebuf + xbuf[(t+1)&1] ready

        // ---- 8. epilogue (all threads, 1 element each) ----
        {
            float ai = gatebuf[0 * 528 + er * 33 + ec] + bi;
            float af = gatebuf[1 * 528 + er * 33 + ec] + bf;
            float ao = gatebuf[2 * 528 + er * 33 + ec] + bo;
            float ag = gatebuf[3 * 528 + er * 33 + ec] + bg;
            float ig = 1.f / (1.f + __expf(-ai));
            float fg = 1.f / (1.f + __expf(-af));
            float og = 1.f / (1.f + __expf(-ao));
            float gg = 2.f / (1.f + __expf(-2.f * ag)) - 1.f;   // tanh
            c_state = fg * c_state + ig * gg;
            float hv = og * (2.f / (1.f + __expf(-2.f * c_state)) - 1.f);

            float pn = __shfl_down(hv, 1);
            if ((ec & 1) == 0) {
                _Float16 f0 = (_Float16)hv, f1 = (_Float16)pn;
                u16 b0, b1;
                __builtin_memcpy(&b0, &f0, 2); __builtin_memcpy(&b1, &f1, 2);
                const u32 wtag = 0xB000u | ((u32)((t + 1) >> 1) & 1u);
                u32 lo = ((u32)b0 << 16) | wtag;
                u32 hi = ((u32)b1 << 16) | wtag;
                u64 v = (u64)lo | ((u64)hi << 32);
                __hip_atomic_store(hq + (size_t)((t + 1) & 1) * (NBHH / 2)
                                   + (size_t)gn * 256 + (gh >> 1), v, AQ, SC);
            }
            if (!isx) houts[t & 1][tid] = hv;     // rows 0-7: hand to x-waves
            else out[(size_t)gn * (TT * HH) + (size_t)t * HH + gh] = hv;  // rows 8-15
        }
        // no barrier: houts(t) read at t+1 after A; gatebuf rewritten after A;
        // hlds restaged pre-A(t+1), readers done pre-B(t).
    }

    // ---- tail: flush handed rows for t = TT-1 ----
    barrier_lgkm();
    if (isx) {
        float hvp = houts[(TT - 1) & 1][xtid];
        out[(size_t)(row0 + (xtid >> 5)) * (TT * HH)
            + (size_t)(TT - 1) * HH + (cg << 5) + (xtid & 31)] = hvp;
    }
}

extern "C" void kernel_launch(void* const* d_in, const int* in_sizes, int n_in,
                              void* d_out, int out_size, void* d_ws, size_t ws_size,
                              hipStream_t stream) {
    const float* x  = (const float*)d_in[0];
    const float* h0 = (const float*)d_in[1];
    const float* Wx = (const float*)d_in[2];
    const float* Wh = (const float*)d_in[3];
    const float* b  = (const float*)d_in[4];
    float* out = (float*)d_out;

    u64* hq = (u64*)d_ws;   // 2 slots x 64 x 512 x u32 = 256 KB

    init_ws_kernel<<<128, 256, 0, stream>>>(hq);
    lstm_persist<<<dim3(64), dim3(512), 0, stream>>>(x, h0, Wx, Wh, b, out, hq);
}